// Round 9
// baseline (81.187 us; speedup 1.0000x reference)
//
#include <hip/hip_runtime.h>
#include <hip/hip_bf16.h>

// Shapes: c1[4,256,128,128], c2[4,512,64,64], out[4,256,64,64],
//         w_refine[32,256], w_refine2[32,512]  -> result[4,256,128,128] (f32)

typedef float f32x4 __attribute__((ext_vector_type(4)));
typedef float f32x2 __attribute__((ext_vector_type(2)));

#define SCL (63.0f / 127.0f)

// ---------------- K2: kfs = c2 @ w_refine2^T at 64x64 (UNNORMALIZED), [n*4096 pix][32]
// 256 blocks x 1024 thr = 16 waves: wave = (cg in 8 x og in 2). 1 pixel/lane.
__global__ __launch_bounds__(1024) void k_kfs(const float* __restrict__ c2,
                                              const float* __restrict__ wr2,
                                              float* __restrict__ kfs) {
    __shared__ float red[8 * 32 * 66];     // 67.6 KB
    int b = blockIdx.x;                    // 64 blocks per n
    int n = b >> 6;
    int pblk = (b & 63) * 64;
    int t = threadIdx.x;
    int lane = t & 63;
    int w = t >> 6;
    int cg = __builtin_amdgcn_readfirstlane(w & 7);    // 64 ch
    int og = __builtin_amdgcn_readfirstlane(w >> 3);   // 16 out

    const float* src = c2 + ((size_t)n * 512 + cg * 64) * 4096 + pblk + lane;
    const float* wp  = wr2 + (og * 16) * 512 + cg * 64;

    float acc[16];
#pragma unroll
    for (int o = 0; o < 16; ++o) acc[o] = 0.f;
#pragma unroll 4
    for (int c = 0; c < 64; ++c) {
        float v = src[(size_t)c * 4096];
#pragma unroll
        for (int o = 0; o < 16; ++o)
            acc[o] = fmaf(v, wp[o * 512 + c], acc[o]);
    }
#pragma unroll
    for (int o = 0; o < 16; ++o)
        red[(cg * 32 + og * 16 + o) * 66 + lane] = acc[o];
    __syncthreads();

    if (t < 512) {
        int px = t & 63, seg = t >> 6;
        float v[4];
#pragma unroll
        for (int j = 0; j < 4; ++j) {
            float r = 0.f;
#pragma unroll
            for (int g = 0; g < 8; ++g) r += red[(g * 32 + seg * 4 + j) * 66 + px];
            v[j] = r;
        }
        f32x4 o4 = { v[0], v[1], v[2], v[3] };
        *(f32x4*)(kfs + ((size_t)n * 4096 + pblk + px) * 32 + seg * 4) = o4;
    }
}

// ---------------- K3: kft = normalize_c( bilinear_up(kfs, 64->128) )
// 4 threads per pixel (quarter = 8 floats). 1024 blocks x 256 thr.
__global__ __launch_bounds__(256) void k_upnorm(const float* __restrict__ kfs,
                                                float* __restrict__ kft) {
    int g = blockIdx.x * 256 + threadIdx.x;
    int p = g >> 2, qt = g & 3;
    int n = p >> 14;
    int rem = p & 16383;
    int y = rem >> 7, x = rem & 127;
    float syf = SCL * (float)y; int y0 = (int)syf; float fy = syf - (float)y0;
    int y1 = min(y0 + 1, 63);
    float sxf = SCL * (float)x; int x0 = (int)sxf; float fx = sxf - (float)x0;
    int x1 = min(x0 + 1, 63);
    size_t base = (size_t)n * 4096 * 32 + qt * 8;
    const f32x4* p00 = (const f32x4*)(kfs + base + ((size_t)(y0 * 64 + x0)) * 32);
    const f32x4* p01 = (const f32x4*)(kfs + base + ((size_t)(y0 * 64 + x1)) * 32);
    const f32x4* p10 = (const f32x4*)(kfs + base + ((size_t)(y1 * 64 + x0)) * 32);
    const f32x4* p11 = (const f32x4*)(kfs + base + ((size_t)(y1 * 64 + x1)) * 32);
    float w00 = (1.f-fy)*(1.f-fx), w01 = (1.f-fy)*fx, w10 = fy*(1.f-fx), w11 = fy*fx;
    float v[8]; float s = 0.f;
#pragma unroll
    for (int j = 0; j < 2; ++j) {
        f32x4 a = p00[j], b = p01[j], c = p10[j], d = p11[j];
#pragma unroll
        for (int tt = 0; tt < 4; ++tt) {
            float r = a[tt]*w00 + b[tt]*w01 + c[tt]*w10 + d[tt]*w11;
            v[4*j + tt] = r;
            s = fmaf(r, r, s);
        }
    }
    s += __shfl_xor(s, 1, 4);
    s += __shfl_xor(s, 2, 4);
    float inv = 1.0f / fmaxf(sqrtf(s), 1e-12f);
    f32x4* dst = (f32x4*)(kft + (size_t)p * 32 + qt * 8);
#pragma unroll
    for (int j = 0; j < 2; ++j) {
        f32x4 t = { v[4*j]*inv, v[4*j+1]*inv, v[4*j+2]*inv, v[4*j+3]*inv };
        dst[j] = t;
    }
}

// ---------------- K_FQ2: q GEMM -> normalize -> energies -> softmax -> 16 weights -> wbuf
// 1024 blocks x 512 thr (= 32 waves/CU). Block = 64-px half-row.
// Phase1: 8 waves = cg(4) x og(2); 1 px/lane, 16 outputs/wave. red[4*32*66]=8448 f (33.8KB).
// After reduce: qlds[64][33] @0 (2112) | wlds[64][17] @2112 (1088).
__global__ __launch_bounds__(512) void k_fq2(const float* __restrict__ c1,
                                             const float* __restrict__ wr,
                                             const float* __restrict__ kft,
                                             float* __restrict__ wbuf) {
    __shared__ float smem[8448];
    const int WOFF = 2112;
    int b = blockIdx.x;                    // 256 blocks per n
    int n = b >> 8;
    int pblk = (b & 255) * 64;             // 64-px chunk: row y, half xh
    int y = pblk >> 7;
    int xh = pblk & 127;                   // 0 or 64
    int t = threadIdx.x;
    int lane = t & 63;
    int w = t >> 6;
    int cg = __builtin_amdgcn_readfirstlane(w & 3);    // 64 ch
    int og = __builtin_amdgcn_readfirstlane(w >> 2);   // 16 out

    // ---- phase 1: raw q GEMM (1 px per lane)
    {
        const float* src = c1 + ((size_t)n * 256 + cg * 64) * 16384 + pblk + lane;
        const float* wp  = wr + (og * 16) * 256 + cg * 64;
        float acc[16];
#pragma unroll
        for (int o = 0; o < 16; ++o) acc[o] = 0.f;
#pragma unroll 4
        for (int c = 0; c < 64; ++c) {
            float v = src[(size_t)c * 16384];              // coalesced 256B/wave
#pragma unroll
            for (int o = 0; o < 16; ++o)
                acc[o] = fmaf(v, wp[o * 256 + c], acc[o]); // wave-uniform s_load
        }
#pragma unroll
        for (int o = 0; o < 16; ++o)
            smem[(cg * 32 + og * 16 + o) * 66 + lane] = acc[o];
    }
    __syncthreads();

    // ---- reduce 4 cg partials (256 thr: px x 4 output-groups), park in regs, overlay qlds
    float v8[8];
    {
        int px = t & 63, kg = (t >> 6) & 3;
        if (t < 256) {
#pragma unroll
            for (int o = 0; o < 8; ++o) {
                int k = kg * 8 + o;
                v8[o] = smem[(0 * 32 + k) * 66 + px] + smem[(1 * 32 + k) * 66 + px]
                      + smem[(2 * 32 + k) * 66 + px] + smem[(3 * 32 + k) * 66 + px];
            }
        }
    }
    __syncthreads();
    if (t < 256) {
        int px = t & 63, kg = (t >> 6) & 3;
#pragma unroll
        for (int o = 0; o < 8; ++o) smem[px * 33 + kg * 8 + o] = v8[o];
    }
    __syncthreads();

    // ---- phase 2: t<256, 4 threads per pixel (8 ch each): energies, softmax, scatter
    if (t < 256) {
        int px = t >> 2, qt = t & 3;
        int x = xh + px;
        int ybase2 = min((int)(SCL * (float)max(y - 2, 0)), 60);
        int xbase2 = min((int)(SCL * (float)max(x - 2, 0)), 60);

        float qv[8];
#pragma unroll
        for (int j = 0; j < 8; ++j) qv[j] = smem[px * 33 + qt * 8 + j];
        float qs = 0.f;
#pragma unroll
        for (int j = 0; j < 8; ++j) qs = fmaf(qv[j], qv[j], qs);

        float d[9];
#pragma unroll
        for (int ky = 0; ky < 3; ++ky) {
            int ny = y + 2 * ky - 2;
            bool rowOK = (ny >= 0) && (ny < 128);
#pragma unroll
            for (int kx = 0; kx < 3; ++kx) {
                int nx = x + 2 * kx - 2;
                float acc = 0.f;
                if (rowOK && nx >= 0 && nx < 128) {
                    const f32x4* kp = (const f32x4*)(kft + ((size_t)n * 16384 + ny * 128 + nx) * 32 + qt * 8);
                    f32x4 a = kp[0], b2 = kp[1];
                    acc = fmaf(a[0],  qv[0], acc); acc = fmaf(a[1],  qv[1], acc);
                    acc = fmaf(a[2],  qv[2], acc); acc = fmaf(a[3],  qv[3], acc);
                    acc = fmaf(b2[0], qv[4], acc); acc = fmaf(b2[1], qv[5], acc);
                    acc = fmaf(b2[2], qv[6], acc); acc = fmaf(b2[3], qv[7], acc);
                }
                d[ky * 3 + kx] = acc;
            }
        }
        qs += __shfl_xor(qs, 1, 4); qs += __shfl_xor(qs, 2, 4);
#pragma unroll
        for (int k = 0; k < 9; ++k) {
            d[k] += __shfl_xor(d[k], 1, 4);
            d[k] += __shfl_xor(d[k], 2, 4);
        }
        float qinv = 1.0f / fmaxf(sqrtf(qs), 1e-12f);

        float e[9];
        float m = d[0] * qinv;
#pragma unroll
        for (int k = 0; k < 9; ++k) { e[k] = d[k] * qinv; if (k) m = fmaxf(m, e[k]); }
        float ssum = 0.f;
#pragma unroll
        for (int k = 0; k < 9; ++k) { e[k] = __expf(e[k] - m); ssum += e[k]; }
        float rinv = 1.0f / ssum;

        // scatter (4 replica lanes, lockstep same-address writes = safe)
        float* wp = smem + WOFF + px * 17;
#pragma unroll
        for (int i = 0; i < 16; ++i) wp[i] = 0.f;
#pragma unroll
        for (int ky = 0; ky < 3; ++ky) {
            int ny = y + 2 * ky - 2;
            if (ny < 0 || ny > 127) continue;
            float syf = SCL * (float)ny; int iy0 = (int)syf; float fy = syf - (float)iy0;
            int iy1 = min(iy0 + 1, 63);
            int r0 = (iy0 - ybase2) * 4, r1 = (iy1 - ybase2) * 4;
#pragma unroll
            for (int kx = 0; kx < 3; ++kx) {
                int nx = x + 2 * kx - 2;
                if (nx < 0 || nx > 127) continue;
                float sxf = SCL * (float)nx; int ix0 = (int)sxf; float fx = sxf - (float)ix0;
                int ix1 = min(ix0 + 1, 63);
                float a = e[ky * 3 + kx] * rinv;
                wp[r0 + (ix0 - xbase2)] += a * (1.f - fy) * (1.f - fx);
                wp[r0 + (ix1 - xbase2)] += a * (1.f - fy) * fx;
                wp[r1 + (ix0 - xbase2)] += a * fy * (1.f - fx);
                wp[r1 + (ix1 - xbase2)] += a * fy * fx;
            }
        }
    }
    __syncthreads();

    // ---- transposed coalesced store: 64 px x 16 i, 2 per thread
    {
        int pg = n * 16384 + pblk;
#pragma unroll
        for (int r = 0; r < 2; ++r) {
            int u = t + 512 * r;       // 0..1023 = 16 i x 64 px
            int i = u >> 6, pxs = u & 63;
            wbuf[i * 65536 + pg + pxs] = smem[WOFF + pxs * 17 + i];
        }
    }
}

// ---------------- K_AGG2: aggregate out planes with combined weights.
// grid 2048 = n(4) x y(128) x cg(4); 256 thr = (px2 in 64 x-pairs) x (cq in 4).
// Pair-sharing: 20 LDS reads + cndmask shift serve 2 outputs (scratch-free, R8-proven).
__global__ __launch_bounds__(256) void k_agg2(const float* __restrict__ wbuf,
                                              const float* __restrict__ outp,
                                              float* __restrict__ res) {
    __shared__ float wlds[128 * 17];   // 2176
    __shared__ float tile[8 * 260];    // 2080
    int b = blockIdx.x;
    int cg = b & 3, y = (b >> 2) & 127, n = b >> 9;
    int t = threadIdx.x;
    int px2 = t & 63, cq = t >> 6;

    int ybase = min((int)(SCL * (float)max(y - 2, 0)), 60);
    int pix = n * 16384 + y * 128;

    // stage per-pixel weights: 16 x 128 floats, coalesced
#pragma unroll
    for (int k = 0; k < 8; ++k) {
        int u = t + 256 * k;
        int i = u >> 7, xx = u & 127;
        wlds[xx * 17 + i] = wbuf[i * 65536 + pix + xx];
    }
    __syncthreads();

    int x0 = px2 * 2, x1 = x0 + 1;
    int xb0 = min((int)(SCL * (float)max(x0 - 2, 0)), 60);
    int xb1 = min((int)(SCL * (float)max(x1 - 2, 0)), 60);
    bool sh = (xb1 != xb0);
    float wA[16], wB[16];
#pragma unroll
    for (int i = 0; i < 16; ++i) {     // compile-time indices only
        wA[i] = wlds[x0 * 17 + i];
        wB[i] = wlds[x1 * 17 + i];
    }

    const float* ob = outp + ((size_t)n * 256 + cg * 64) * 4096 + ybase * 64;
    float* rb = res + ((size_t)n * 256 + cg * 64) * 16384 + y * 128 + x0;

#pragma unroll 1
    for (int batch = 0; batch < 8; ++batch) {
        __syncthreads();
        // stage 8 channels x 4 rows x 64 cols
#pragma unroll
        for (int k = 0; k < 2; ++k) {
            int u = t + 256 * k;               // 0..511 = 8ch x 64 f32x4
            int cl = u >> 6, seg = u & 63;
            f32x4 v = *(const f32x4*)(ob + (size_t)(batch * 8 + cl) * 4096 + seg * 4);
            *(f32x4*)&tile[cl * 260 + seg * 4] = v;
        }
        __syncthreads();
#pragma unroll
        for (int cc = 0; cc < 2; ++cc) {
            int c = cq * 2 + cc;
            const float* tp = &tile[c * 260 + xb0];
            float a0 = 0.f, a1 = 0.f;
#pragma unroll
            for (int r = 0; r < 4; ++r) {
                float c0 = tp[r * 64 + 0];
                float c1 = tp[r * 64 + 1];
                float c2 = tp[r * 64 + 2];
                float c3 = tp[r * 64 + 3];
                float c4 = tp[r * 64 + 4];     // used only when sh (always in LDS bounds)
                a0 = fmaf(wA[r*4+0], c0, a0);
                a0 = fmaf(wA[r*4+1], c1, a0);
                a0 = fmaf(wA[r*4+2], c2, a0);
                a0 = fmaf(wA[r*4+3], c3, a0);
                float s0 = sh ? c1 : c0;
                float s1 = sh ? c2 : c1;
                float s2 = sh ? c3 : c2;
                float s3 = sh ? c4 : c3;
                a1 = fmaf(wB[r*4+0], s0, a1);
                a1 = fmaf(wB[r*4+1], s1, a1);
                a1 = fmaf(wB[r*4+2], s2, a1);
                a1 = fmaf(wB[r*4+3], s3, a1);
            }
            f32x2 st = { a0, a1 };
            *(f32x2*)(rb + (size_t)(batch * 8 + c) * 16384) = st;   // coalesced 8B store
        }
    }
}

extern "C" void kernel_launch(void* const* d_in, const int* in_sizes, int n_in,
                              void* d_out, int out_size, void* d_ws, size_t ws_size,
                              hipStream_t stream) {
    const float* c1   = (const float*)d_in[0];
    const float* c2   = (const float*)d_in[1];
    const float* outp = (const float*)d_in[2];
    const float* wr   = (const float*)d_in[3];
    const float* wr2  = (const float*)d_in[4];
    float* res = (float*)d_out;

    // ws: kfs 2.10MB | kft 8.39MB | wbuf 4.19MB
    float* kfs_ws = (float*)d_ws;
    float* kft_ws = (float*)((char*)d_ws + 2097152);
    float* w_ws   = (float*)((char*)d_ws + 2097152 + 8388608);

    hipLaunchKernelGGL(k_kfs,    dim3(256),  dim3(1024), 0, stream, c2, wr2, kfs_ws);
    hipLaunchKernelGGL(k_upnorm, dim3(1024), dim3(256),  0, stream, kfs_ws, kft_ws);
    hipLaunchKernelGGL(k_fq2,    dim3(1024), dim3(512),  0, stream, c1, wr, kft_ws, w_ws);
    hipLaunchKernelGGL(k_agg2,   dim3(2048), dim3(256),  0, stream, w_ws, outp, res);
}

// Round 10
// 79.726 us; speedup vs baseline: 1.0183x; 1.0183x over previous
//
#include <hip/hip_runtime.h>
#include <hip/hip_bf16.h>

// Shapes: c1[4,256,128,128], c2[4,512,64,64], out[4,256,64,64],
//         w_refine[32,256], w_refine2[32,512]  -> result[4,256,128,128] (f32)

typedef float f32x4 __attribute__((ext_vector_type(4)));
typedef float f32x2 __attribute__((ext_vector_type(2)));

#define SCL (63.0f / 127.0f)

// ---------------- K2: kfs = c2 @ w_refine2^T at 64x64 (UNNORMALIZED), [n*4096 pix][32]
__global__ __launch_bounds__(1024) void k_kfs(const float* __restrict__ c2,
                                              const float* __restrict__ wr2,
                                              float* __restrict__ kfs) {
    __shared__ float red[8 * 32 * 66];     // 67.6 KB
    int b = blockIdx.x;                    // 64 blocks per n
    int n = b >> 6;
    int pblk = (b & 63) * 64;
    int t = threadIdx.x;
    int lane = t & 63;
    int w = t >> 6;
    int cg = __builtin_amdgcn_readfirstlane(w & 7);    // 64 ch
    int og = __builtin_amdgcn_readfirstlane(w >> 3);   // 16 out

    const float* src = c2 + ((size_t)n * 512 + cg * 64) * 4096 + pblk + lane;
    const float* wp  = wr2 + (og * 16) * 512 + cg * 64;

    float acc[16];
#pragma unroll
    for (int o = 0; o < 16; ++o) acc[o] = 0.f;
#pragma unroll 4
    for (int c = 0; c < 64; ++c) {
        float v = src[(size_t)c * 4096];
#pragma unroll
        for (int o = 0; o < 16; ++o)
            acc[o] = fmaf(v, wp[o * 512 + c], acc[o]);
    }
#pragma unroll
    for (int o = 0; o < 16; ++o)
        red[(cg * 32 + og * 16 + o) * 66 + lane] = acc[o];
    __syncthreads();

    if (t < 512) {
        int px = t & 63, seg = t >> 6;
        float v[4];
#pragma unroll
        for (int j = 0; j < 4; ++j) {
            float r = 0.f;
#pragma unroll
            for (int g = 0; g < 8; ++g) r += red[(g * 32 + seg * 4 + j) * 66 + px];
            v[j] = r;
        }
        f32x4 o4 = { v[0], v[1], v[2], v[3] };
        *(f32x4*)(kfs + ((size_t)n * 4096 + pblk + px) * 32 + seg * 4) = o4;
    }
}

// ---------------- K3: kft = normalize_c( bilinear_up(kfs, 64->128) )
__global__ __launch_bounds__(256) void k_upnorm(const float* __restrict__ kfs,
                                                float* __restrict__ kft) {
    int g = blockIdx.x * 256 + threadIdx.x;
    int p = g >> 2, qt = g & 3;
    int n = p >> 14;
    int rem = p & 16383;
    int y = rem >> 7, x = rem & 127;
    float syf = SCL * (float)y; int y0 = (int)syf; float fy = syf - (float)y0;
    int y1 = min(y0 + 1, 63);
    float sxf = SCL * (float)x; int x0 = (int)sxf; float fx = sxf - (float)x0;
    int x1 = min(x0 + 1, 63);
    size_t base = (size_t)n * 4096 * 32 + qt * 8;
    const f32x4* p00 = (const f32x4*)(kfs + base + ((size_t)(y0 * 64 + x0)) * 32);
    const f32x4* p01 = (const f32x4*)(kfs + base + ((size_t)(y0 * 64 + x1)) * 32);
    const f32x4* p10 = (const f32x4*)(kfs + base + ((size_t)(y1 * 64 + x0)) * 32);
    const f32x4* p11 = (const f32x4*)(kfs + base + ((size_t)(y1 * 64 + x1)) * 32);
    float w00 = (1.f-fy)*(1.f-fx), w01 = (1.f-fy)*fx, w10 = fy*(1.f-fx), w11 = fy*fx;
    float v[8]; float s = 0.f;
#pragma unroll
    for (int j = 0; j < 2; ++j) {
        f32x4 a = p00[j], b = p01[j], c = p10[j], d = p11[j];
#pragma unroll
        for (int tt = 0; tt < 4; ++tt) {
            float r = a[tt]*w00 + b[tt]*w01 + c[tt]*w10 + d[tt]*w11;
            v[4*j + tt] = r;
            s = fmaf(r, r, s);
        }
    }
    s += __shfl_xor(s, 1, 4);
    s += __shfl_xor(s, 2, 4);
    float inv = 1.0f / fmaxf(sqrtf(s), 1e-12f);
    f32x4* dst = (f32x4*)(kft + (size_t)p * 32 + qt * 8);
#pragma unroll
    for (int j = 0; j < 2; ++j) {
        f32x4 t = { v[4*j]*inv, v[4*j+1]*inv, v[4*j+2]*inv, v[4*j+3]*inv };
        dst[j] = t;
    }
}

// ---------------- K_FQ3: q GEMM (prefetched) -> normalize -> energies -> softmax -> weights -> wbuf
// 512 blocks x 512 thr; block = row y of image n (R6-proven geometry).
// LDS: phase1 red[4cg][32k][130] (16640 f); after: qlds[128][33] @0 | wlds[128][17] @4224.
__global__ __launch_bounds__(512) void k_fq3(const float* __restrict__ c1,
                                             const float* __restrict__ wr,
                                             const float* __restrict__ kft,
                                             float* __restrict__ wbuf) {
    __shared__ float smem[16640];
    const int WOFF = 4224;
    int b = blockIdx.x;                    // 128 blocks per n
    int n = b >> 7;
    int y = b & 127;
    int pblk = y * 128;
    int t = threadIdx.x;
    int lane = t & 63;
    int w = t >> 6;
    int cg = __builtin_amdgcn_readfirstlane(w & 3);    // 64 ch
    int og = __builtin_amdgcn_readfirstlane(w >> 2);   // 16 out

    // ---- phase 1: raw q GEMM, double-buffered prefetch (no runtime-indexed arrays)
    {
        const float* src = c1 + ((size_t)n * 256 + cg * 64) * 16384 + pblk + lane * 2;
        const float* wp  = wr + (og * 16) * 256 + cg * 64;
        float acc0[16], acc1[16];
#pragma unroll
        for (int o = 0; o < 16; ++o) { acc0[o] = 0.f; acc1[o] = 0.f; }
        f32x2 n0 = *(const f32x2*)(src + (size_t)0 * 16384);
        f32x2 n1 = *(const f32x2*)(src + (size_t)1 * 16384);
        f32x2 n2 = *(const f32x2*)(src + (size_t)2 * 16384);
        f32x2 n3 = *(const f32x2*)(src + (size_t)3 * 16384);
#pragma unroll
        for (int cb = 0; cb < 16; ++cb) {
            f32x2 u0 = n0, u1 = n1, u2 = n2, u3 = n3;
            if (cb < 15) {                     // issue next chunk BEFORE this chunk's FMAs
                const float* s2 = src + (size_t)(cb * 4 + 4) * 16384;
                n0 = *(const f32x2*)(s2 + (size_t)0 * 16384);
                n1 = *(const f32x2*)(s2 + (size_t)1 * 16384);
                n2 = *(const f32x2*)(s2 + (size_t)2 * 16384);
                n3 = *(const f32x2*)(s2 + (size_t)3 * 16384);
            }
#pragma unroll
            for (int o = 0; o < 16; ++o) {
                float w0 = wp[o * 256 + cb * 4 + 0];
                float w1 = wp[o * 256 + cb * 4 + 1];
                float w2 = wp[o * 256 + cb * 4 + 2];
                float w3 = wp[o * 256 + cb * 4 + 3];
                acc0[o] = fmaf(u0[0], w0, acc0[o]); acc1[o] = fmaf(u0[1], w0, acc1[o]);
                acc0[o] = fmaf(u1[0], w1, acc0[o]); acc1[o] = fmaf(u1[1], w1, acc1[o]);
                acc0[o] = fmaf(u2[0], w2, acc0[o]); acc1[o] = fmaf(u2[1], w2, acc1[o]);
                acc0[o] = fmaf(u3[0], w3, acc0[o]); acc1[o] = fmaf(u3[1], w3, acc1[o]);
            }
        }
#pragma unroll
        for (int o = 0; o < 16; ++o) {
            f32x2 pr = { acc0[o], acc1[o] };
            *(f32x2*)&smem[(cg * 32 + og * 16 + o) * 130 + lane * 2] = pr;
        }
    }
    __syncthreads();

    // ---- reduce 4 cg partials; park in regs, then overlay qlds[128][33]
    float v16[16];
    {
        int px = t & 127, half = (t >> 7) & 1;
        if (t < 256) {
#pragma unroll
            for (int o = 0; o < 16; ++o) {
                v16[o] = smem[(0 * 32 + half * 16 + o) * 130 + px]
                       + smem[(1 * 32 + half * 16 + o) * 130 + px]
                       + smem[(2 * 32 + half * 16 + o) * 130 + px]
                       + smem[(3 * 32 + half * 16 + o) * 130 + px];
            }
        }
    }
    __syncthreads();
    if (t < 256) {
        int px = t & 127, half = (t >> 7) & 1;
#pragma unroll
        for (int o = 0; o < 16; ++o) smem[px * 33 + half * 16 + o] = v16[o];
    }
    __syncthreads();

    // ---- phase 2: 4 threads per pixel (8 channels each): energies, softmax, scatter
    {
        int px = t >> 2, qt = t & 3;
        int x = px;
        int ybase2 = min((int)(SCL * (float)max(y - 2, 0)), 60);
        int xbase2 = min((int)(SCL * (float)max(x - 2, 0)), 60);

        float qv[8];
#pragma unroll
        for (int j = 0; j < 8; ++j) qv[j] = smem[px * 33 + qt * 8 + j];
        float qs = 0.f;
#pragma unroll
        for (int j = 0; j < 8; ++j) qs = fmaf(qv[j], qv[j], qs);

        float d[9];
#pragma unroll
        for (int ky = 0; ky < 3; ++ky) {
            int ny = y + 2 * ky - 2;
            bool rowOK = (ny >= 0) && (ny < 128);
#pragma unroll
            for (int kx = 0; kx < 3; ++kx) {
                int nx = x + 2 * kx - 2;
                float acc = 0.f;
                if (rowOK && nx >= 0 && nx < 128) {
                    const f32x4* kp = (const f32x4*)(kft + ((size_t)n * 16384 + ny * 128 + nx) * 32 + qt * 8);
                    f32x4 a = kp[0], b2 = kp[1];
                    acc = fmaf(a[0],  qv[0], acc); acc = fmaf(a[1],  qv[1], acc);
                    acc = fmaf(a[2],  qv[2], acc); acc = fmaf(a[3],  qv[3], acc);
                    acc = fmaf(b2[0], qv[4], acc); acc = fmaf(b2[1], qv[5], acc);
                    acc = fmaf(b2[2], qv[6], acc); acc = fmaf(b2[3], qv[7], acc);
                }
                d[ky * 3 + kx] = acc;
            }
        }
        qs += __shfl_xor(qs, 1, 4); qs += __shfl_xor(qs, 2, 4);
#pragma unroll
        for (int k = 0; k < 9; ++k) {
            d[k] += __shfl_xor(d[k], 1, 4);
            d[k] += __shfl_xor(d[k], 2, 4);
        }
        float qinv = 1.0f / fmaxf(sqrtf(qs), 1e-12f);

        float e[9];
        float m = d[0] * qinv;
#pragma unroll
        for (int k = 0; k < 9; ++k) { e[k] = d[k] * qinv; if (k) m = fmaxf(m, e[k]); }
        float ssum = 0.f;
#pragma unroll
        for (int k = 0; k < 9; ++k) { e[k] = __expf(e[k] - m); ssum += e[k]; }
        float rinv = 1.0f / ssum;

        // scatter (4 replica lanes, lockstep same-address writes = safe)
        float* wp = smem + WOFF + px * 17;
#pragma unroll
        for (int i = 0; i < 16; ++i) wp[i] = 0.f;
#pragma unroll
        for (int ky = 0; ky < 3; ++ky) {
            int ny = y + 2 * ky - 2;
            if (ny < 0 || ny > 127) continue;
            float syf = SCL * (float)ny; int iy0 = (int)syf; float fy = syf - (float)iy0;
            int iy1 = min(iy0 + 1, 63);
            int r0 = (iy0 - ybase2) * 4, r1 = (iy1 - ybase2) * 4;
#pragma unroll
            for (int kx = 0; kx < 3; ++kx) {
                int nx = x + 2 * kx - 2;
                if (nx < 0 || nx > 127) continue;
                float sxf = SCL * (float)nx; int ix0 = (int)sxf; float fx = sxf - (float)ix0;
                int ix1 = min(ix0 + 1, 63);
                float a = e[ky * 3 + kx] * rinv;
                wp[r0 + (ix0 - xbase2)] += a * (1.f - fy) * (1.f - fx);
                wp[r0 + (ix1 - xbase2)] += a * (1.f - fy) * fx;
                wp[r1 + (ix0 - xbase2)] += a * fy * (1.f - fx);
                wp[r1 + (ix1 - xbase2)] += a * fy * fx;
            }
        }
    }
    __syncthreads();

    // transposed coalesced store: 128 px x 16 i, 4 per thread
    int sx = t & 127, i0 = t >> 7;
    int pg = n * 16384 + y * 128 + sx;
#pragma unroll
    for (int r = 0; r < 4; ++r) {
        int i = r * 4 + i0;
        wbuf[i * 65536 + pg] = smem[WOFF + sx * 17 + i];
    }
}

// ---------------- K_AGG3: aggregation with DIRECT global window reads (no tile staging).
// grid 2048 = n(4) x y(128) x cg(4); 256 thr = (px2 in 64 x-pairs) x (cq in 4, 16 ch each).
// Per channel: 4 rows x 5 dword loads (lane-overlapping, L1/L2-served) + pair-shared FMA.
__global__ __launch_bounds__(256) void k_agg3(const float* __restrict__ wbuf,
                                              const float* __restrict__ outp,
                                              float* __restrict__ res) {
    __shared__ float wlds[128 * 17];   // 8.7 KB only
    int b = blockIdx.x;
    int cg = b & 3, y = (b >> 2) & 127, n = b >> 9;
    int t = threadIdx.x;
    int px2 = t & 63, cq = t >> 6;

    int ybase = min((int)(SCL * (float)max(y - 2, 0)), 60);
    int pix = n * 16384 + y * 128;

    // stage per-pixel weights: 16 x 128 floats, coalesced
#pragma unroll
    for (int k = 0; k < 8; ++k) {
        int u = t + 256 * k;
        int i = u >> 7, xx = u & 127;
        wlds[xx * 17 + i] = wbuf[i * 65536 + pix + xx];
    }
    __syncthreads();

    int x0 = px2 * 2, x1 = x0 + 1;
    int xb0 = min((int)(SCL * (float)max(x0 - 2, 0)), 60);
    int xb1 = min((int)(SCL * (float)max(x1 - 2, 0)), 60);
    bool sh = (xb1 != xb0);
    int j4 = sh ? 4 : 3;               // OOB-safe 5th column (sh=1 => xb0<=59 => xb0+4<=63)
    float wA[16], wB[16];
#pragma unroll
    for (int i = 0; i < 16; ++i) {     // compile-time indices only
        wA[i] = wlds[x0 * 17 + i];
        wB[i] = wlds[x1 * 17 + i];
    }

    const float* ob = outp + ((size_t)n * 256 + cg * 64 + cq * 16) * 4096 + ybase * 64 + xb0;
    float* rb = res + ((size_t)n * 256 + cg * 64 + cq * 16) * 16384 + y * 128 + x0;

#pragma unroll 2
    for (int i = 0; i < 16; ++i) {     // 16 channels per thread
        const float* tp = ob + (size_t)i * 4096;
        float a0 = 0.f, a1 = 0.f;
#pragma unroll
        for (int r = 0; r < 4; ++r) {
            float c0 = tp[r * 64 + 0];
            float c1 = tp[r * 64 + 1];
            float c2 = tp[r * 64 + 2];
            float c3 = tp[r * 64 + 3];
            float c4 = tp[r * 64 + j4];
            a0 = fmaf(wA[r*4+0], c0, a0);
            a0 = fmaf(wA[r*4+1], c1, a0);
            a0 = fmaf(wA[r*4+2], c2, a0);
            a0 = fmaf(wA[r*4+3], c3, a0);
            float s0 = sh ? c1 : c0;
            float s1 = sh ? c2 : c1;
            float s2 = sh ? c3 : c2;
            float s3 = sh ? c4 : c3;
            a1 = fmaf(wB[r*4+0], s0, a1);
            a1 = fmaf(wB[r*4+1], s1, a1);
            a1 = fmaf(wB[r*4+2], s2, a1);
            a1 = fmaf(wB[r*4+3], s3, a1);
        }
        f32x2 st = { a0, a1 };
        *(f32x2*)(rb + (size_t)i * 16384) = st;   // coalesced 8B store
    }
}

extern "C" void kernel_launch(void* const* d_in, const int* in_sizes, int n_in,
                              void* d_out, int out_size, void* d_ws, size_t ws_size,
                              hipStream_t stream) {
    const float* c1   = (const float*)d_in[0];
    const float* c2   = (const float*)d_in[1];
    const float* outp = (const float*)d_in[2];
    const float* wr   = (const float*)d_in[3];
    const float* wr2  = (const float*)d_in[4];
    float* res = (float*)d_out;

    // ws: kfs 2.10MB | kft 8.39MB | wbuf 4.19MB
    float* kfs_ws = (float*)d_ws;
    float* kft_ws = (float*)((char*)d_ws + 2097152);
    float* w_ws   = (float*)((char*)d_ws + 2097152 + 8388608);

    hipLaunchKernelGGL(k_kfs,    dim3(256),  dim3(1024), 0, stream, c2, wr2, kfs_ws);
    hipLaunchKernelGGL(k_upnorm, dim3(1024), dim3(256),  0, stream, kfs_ws, kft_ws);
    hipLaunchKernelGGL(k_fq3,    dim3(512),  dim3(512),  0, stream, c1, wr, kft_ws, w_ws);
    hipLaunchKernelGGL(k_agg3,   dim3(2048), dim3(256),  0, stream, w_ws, outp, res);
}

// Round 11
// 76.266 us; speedup vs baseline: 1.0645x; 1.0454x over previous
//
#include <hip/hip_runtime.h>
#include <hip/hip_bf16.h>

// Shapes: c1[4,256,128,128], c2[4,512,64,64], out[4,256,64,64],
//         w_refine[32,256], w_refine2[32,512]  -> result[4,256,128,128] (f32)

typedef float f32x4 __attribute__((ext_vector_type(4)));
typedef float f32x2 __attribute__((ext_vector_type(2)));

#define SCL (63.0f / 127.0f)

// ---------------- K2: kfs = c2 @ w_refine2^T at 64x64 (UNNORMALIZED), [n*4096 pix][32]
__global__ __launch_bounds__(1024) void k_kfs(const float* __restrict__ c2,
                                              const float* __restrict__ wr2,
                                              float* __restrict__ kfs) {
    __shared__ float red[8 * 32 * 66];     // 67.6 KB
    int b = blockIdx.x;                    // 64 blocks per n
    int n = b >> 6;
    int pblk = (b & 63) * 64;
    int t = threadIdx.x;
    int lane = t & 63;
    int w = t >> 6;
    int cg = __builtin_amdgcn_readfirstlane(w & 7);    // 64 ch
    int og = __builtin_amdgcn_readfirstlane(w >> 3);   // 16 out

    const float* src = c2 + ((size_t)n * 512 + cg * 64) * 4096 + pblk + lane;
    const float* wp  = wr2 + (og * 16) * 512 + cg * 64;

    float acc[16];
#pragma unroll
    for (int o = 0; o < 16; ++o) acc[o] = 0.f;
#pragma unroll 4
    for (int c = 0; c < 64; ++c) {
        float v = src[(size_t)c * 4096];
#pragma unroll
        for (int o = 0; o < 16; ++o)
            acc[o] = fmaf(v, wp[o * 512 + c], acc[o]);
    }
#pragma unroll
    for (int o = 0; o < 16; ++o)
        red[(cg * 32 + og * 16 + o) * 66 + lane] = acc[o];
    __syncthreads();

    if (t < 512) {
        int px = t & 63, seg = t >> 6;
        float v[4];
#pragma unroll
        for (int j = 0; j < 4; ++j) {
            float r = 0.f;
#pragma unroll
            for (int g = 0; g < 8; ++g) r += red[(g * 32 + seg * 4 + j) * 66 + px];
            v[j] = r;
        }
        f32x4 o4 = { v[0], v[1], v[2], v[3] };
        *(f32x4*)(kfs + ((size_t)n * 4096 + pblk + px) * 32 + seg * 4) = o4;
    }
}

// ---------------- K3: kft = normalize_c( bilinear_up(kfs, 64->128) )
__global__ __launch_bounds__(256) void k_upnorm(const float* __restrict__ kfs,
                                                float* __restrict__ kft) {
    int g = blockIdx.x * 256 + threadIdx.x;
    int p = g >> 2, qt = g & 3;
    int n = p >> 14;
    int rem = p & 16383;
    int y = rem >> 7, x = rem & 127;
    float syf = SCL * (float)y; int y0 = (int)syf; float fy = syf - (float)y0;
    int y1 = min(y0 + 1, 63);
    float sxf = SCL * (float)x; int x0 = (int)sxf; float fx = sxf - (float)x0;
    int x1 = min(x0 + 1, 63);
    size_t base = (size_t)n * 4096 * 32 + qt * 8;
    const f32x4* p00 = (const f32x4*)(kfs + base + ((size_t)(y0 * 64 + x0)) * 32);
    const f32x4* p01 = (const f32x4*)(kfs + base + ((size_t)(y0 * 64 + x1)) * 32);
    const f32x4* p10 = (const f32x4*)(kfs + base + ((size_t)(y1 * 64 + x0)) * 32);
    const f32x4* p11 = (const f32x4*)(kfs + base + ((size_t)(y1 * 64 + x1)) * 32);
    float w00 = (1.f-fy)*(1.f-fx), w01 = (1.f-fy)*fx, w10 = fy*(1.f-fx), w11 = fy*fx;
    float v[8]; float s = 0.f;
#pragma unroll
    for (int j = 0; j < 2; ++j) {
        f32x4 a = p00[j], b = p01[j], c = p10[j], d = p11[j];
#pragma unroll
        for (int tt = 0; tt < 4; ++tt) {
            float r = a[tt]*w00 + b[tt]*w01 + c[tt]*w10 + d[tt]*w11;
            v[4*j + tt] = r;
            s = fmaf(r, r, s);
        }
    }
    s += __shfl_xor(s, 1, 4);
    s += __shfl_xor(s, 2, 4);
    float inv = 1.0f / fmaxf(sqrtf(s), 1e-12f);
    f32x4* dst = (f32x4*)(kft + (size_t)p * 32 + qt * 8);
#pragma unroll
    for (int j = 0; j < 2; ++j) {
        f32x4 t = { v[4*j]*inv, v[4*j+1]*inv, v[4*j+2]*inv, v[4*j+3]*inv };
        dst[j] = t;
    }
}

// ---------------- K_FQ3: q GEMM (prefetched) -> normalize -> energies -> softmax -> weights -> wbuf
// 512 blocks x 512 thr; block = row y of image n.
__global__ __launch_bounds__(512) void k_fq3(const float* __restrict__ c1,
                                             const float* __restrict__ wr,
                                             const float* __restrict__ kft,
                                             float* __restrict__ wbuf) {
    __shared__ float smem[16640];
    const int WOFF = 4224;
    int b = blockIdx.x;                    // 128 blocks per n
    int n = b >> 7;
    int y = b & 127;
    int pblk = y * 128;
    int t = threadIdx.x;
    int lane = t & 63;
    int w = t >> 6;
    int cg = __builtin_amdgcn_readfirstlane(w & 3);    // 64 ch
    int og = __builtin_amdgcn_readfirstlane(w >> 2);   // 16 out

    // ---- phase 1: raw q GEMM, double-buffered prefetch (no runtime-indexed arrays)
    {
        const float* src = c1 + ((size_t)n * 256 + cg * 64) * 16384 + pblk + lane * 2;
        const float* wp  = wr + (og * 16) * 256 + cg * 64;
        float acc0[16], acc1[16];
#pragma unroll
        for (int o = 0; o < 16; ++o) { acc0[o] = 0.f; acc1[o] = 0.f; }
        f32x2 n0 = *(const f32x2*)(src + (size_t)0 * 16384);
        f32x2 n1 = *(const f32x2*)(src + (size_t)1 * 16384);
        f32x2 n2 = *(const f32x2*)(src + (size_t)2 * 16384);
        f32x2 n3 = *(const f32x2*)(src + (size_t)3 * 16384);
#pragma unroll
        for (int cb = 0; cb < 16; ++cb) {
            f32x2 u0 = n0, u1 = n1, u2 = n2, u3 = n3;
            if (cb < 15) {                     // issue next chunk BEFORE this chunk's FMAs
                const float* s2 = src + (size_t)(cb * 4 + 4) * 16384;
                n0 = *(const f32x2*)(s2 + (size_t)0 * 16384);
                n1 = *(const f32x2*)(s2 + (size_t)1 * 16384);
                n2 = *(const f32x2*)(s2 + (size_t)2 * 16384);
                n3 = *(const f32x2*)(s2 + (size_t)3 * 16384);
            }
#pragma unroll
            for (int o = 0; o < 16; ++o) {
                float w0 = wp[o * 256 + cb * 4 + 0];
                float w1 = wp[o * 256 + cb * 4 + 1];
                float w2 = wp[o * 256 + cb * 4 + 2];
                float w3 = wp[o * 256 + cb * 4 + 3];
                acc0[o] = fmaf(u0[0], w0, acc0[o]); acc1[o] = fmaf(u0[1], w0, acc1[o]);
                acc0[o] = fmaf(u1[0], w1, acc0[o]); acc1[o] = fmaf(u1[1], w1, acc1[o]);
                acc0[o] = fmaf(u2[0], w2, acc0[o]); acc1[o] = fmaf(u2[1], w2, acc1[o]);
                acc0[o] = fmaf(u3[0], w3, acc0[o]); acc1[o] = fmaf(u3[1], w3, acc1[o]);
            }
        }
#pragma unroll
        for (int o = 0; o < 16; ++o) {
            f32x2 pr = { acc0[o], acc1[o] };
            *(f32x2*)&smem[(cg * 32 + og * 16 + o) * 130 + lane * 2] = pr;
        }
    }
    __syncthreads();

    // ---- reduce 4 cg partials; park in regs, then overlay qlds[128][33]
    float v16[16];
    {
        int px = t & 127, half = (t >> 7) & 1;
        if (t < 256) {
#pragma unroll
            for (int o = 0; o < 16; ++o) {
                v16[o] = smem[(0 * 32 + half * 16 + o) * 130 + px]
                       + smem[(1 * 32 + half * 16 + o) * 130 + px]
                       + smem[(2 * 32 + half * 16 + o) * 130 + px]
                       + smem[(3 * 32 + half * 16 + o) * 130 + px];
            }
        }
    }
    __syncthreads();
    if (t < 256) {
        int px = t & 127, half = (t >> 7) & 1;
#pragma unroll
        for (int o = 0; o < 16; ++o) smem[px * 33 + half * 16 + o] = v16[o];
    }
    __syncthreads();

    // ---- phase 2: 4 threads per pixel (8 channels each): energies, softmax, scatter
    {
        int px = t >> 2, qt = t & 3;
        int x = px;
        int ybase2 = min((int)(SCL * (float)max(y - 2, 0)), 60);
        int xbase2 = min((int)(SCL * (float)max(x - 2, 0)), 60);

        float qv[8];
#pragma unroll
        for (int j = 0; j < 8; ++j) qv[j] = smem[px * 33 + qt * 8 + j];
        float qs = 0.f;
#pragma unroll
        for (int j = 0; j < 8; ++j) qs = fmaf(qv[j], qv[j], qs);

        float d[9];
#pragma unroll
        for (int ky = 0; ky < 3; ++ky) {
            int ny = y + 2 * ky - 2;
            bool rowOK = (ny >= 0) && (ny < 128);
#pragma unroll
            for (int kx = 0; kx < 3; ++kx) {
                int nx = x + 2 * kx - 2;
                float acc = 0.f;
                if (rowOK && nx >= 0 && nx < 128) {
                    const f32x4* kp = (const f32x4*)(kft + ((size_t)n * 16384 + ny * 128 + nx) * 32 + qt * 8);
                    f32x4 a = kp[0], b2 = kp[1];
                    acc = fmaf(a[0],  qv[0], acc); acc = fmaf(a[1],  qv[1], acc);
                    acc = fmaf(a[2],  qv[2], acc); acc = fmaf(a[3],  qv[3], acc);
                    acc = fmaf(b2[0], qv[4], acc); acc = fmaf(b2[1], qv[5], acc);
                    acc = fmaf(b2[2], qv[6], acc); acc = fmaf(b2[3], qv[7], acc);
                }
                d[ky * 3 + kx] = acc;
            }
        }
        qs += __shfl_xor(qs, 1, 4); qs += __shfl_xor(qs, 2, 4);
#pragma unroll
        for (int k = 0; k < 9; ++k) {
            d[k] += __shfl_xor(d[k], 1, 4);
            d[k] += __shfl_xor(d[k], 2, 4);
        }
        float qinv = 1.0f / fmaxf(sqrtf(qs), 1e-12f);

        float e[9];
        float m = d[0] * qinv;
#pragma unroll
        for (int k = 0; k < 9; ++k) { e[k] = d[k] * qinv; if (k) m = fmaxf(m, e[k]); }
        float ssum = 0.f;
#pragma unroll
        for (int k = 0; k < 9; ++k) { e[k] = __expf(e[k] - m); ssum += e[k]; }
        float rinv = 1.0f / ssum;

        // scatter (4 replica lanes, lockstep same-address writes = safe)
        float* wp = smem + WOFF + px * 17;
#pragma unroll
        for (int i = 0; i < 16; ++i) wp[i] = 0.f;
#pragma unroll
        for (int ky = 0; ky < 3; ++ky) {
            int ny = y + 2 * ky - 2;
            if (ny < 0 || ny > 127) continue;
            float syf = SCL * (float)ny; int iy0 = (int)syf; float fy = syf - (float)iy0;
            int iy1 = min(iy0 + 1, 63);
            int r0 = (iy0 - ybase2) * 4, r1 = (iy1 - ybase2) * 4;
#pragma unroll
            for (int kx = 0; kx < 3; ++kx) {
                int nx = x + 2 * kx - 2;
                if (nx < 0 || nx > 127) continue;
                float sxf = SCL * (float)nx; int ix0 = (int)sxf; float fx = sxf - (float)ix0;
                int ix1 = min(ix0 + 1, 63);
                float a = e[ky * 3 + kx] * rinv;
                wp[r0 + (ix0 - xbase2)] += a * (1.f - fy) * (1.f - fx);
                wp[r0 + (ix1 - xbase2)] += a * (1.f - fy) * fx;
                wp[r1 + (ix0 - xbase2)] += a * fy * (1.f - fx);
                wp[r1 + (ix1 - xbase2)] += a * fy * fx;
            }
        }
    }
    __syncthreads();

    // transposed coalesced store: 128 px x 16 i, 4 per thread
    int sx = t & 127, i0 = t >> 7;
    int pg = n * 16384 + y * 128 + sx;
#pragma unroll
    for (int r = 0; r < 4; ++r) {
        int i = r * 4 + i0;
        wbuf[i * 65536 + pg] = smem[WOFF + sx * 17 + i];
    }
}

// ---------------- K_AGG4: LDS-staged aggregation, double-buffered, 4 batches x 16 ch.
// grid 2048 = n(4) x y(128) x cg(4); 256 thr = (px2 in 64 x-pairs) x (cq wave in 4).
// Staging: thread loads ch (cq+4k), seg=t&63 -> f32x4; regs->LDS next to barrier;
// batch b+1 loads issue BEFORE batch b compute (latency hidden under 4ch x 52 ops).
__global__ __launch_bounds__(256) void k_agg4(const float* __restrict__ wbuf,
                                              const float* __restrict__ outp,
                                              float* __restrict__ res) {
    __shared__ float wlds[128 * 17];   // 2176 f
    __shared__ float tile[16 * 260];   // 4160 f -> total 25.3 KB
    int b = blockIdx.x;
    int cg = b & 3, y = (b >> 2) & 127, n = b >> 9;
    int t = threadIdx.x;
    int px2 = t & 63, cq = t >> 6, seg = t & 63;

    int ybase = min((int)(SCL * (float)max(y - 2, 0)), 60);
    int pix = n * 16384 + y * 128;

    // stage per-pixel weights: 16 x 128 floats, coalesced
#pragma unroll
    for (int k = 0; k < 8; ++k) {
        int u = t + 256 * k;
        int i = u >> 7, xx = u & 127;
        wlds[xx * 17 + i] = wbuf[i * 65536 + pix + xx];
    }
    __syncthreads();

    int x0 = px2 * 2, x1 = x0 + 1;
    int xb0 = min((int)(SCL * (float)max(x0 - 2, 0)), 60);
    int xb1 = min((int)(SCL * (float)max(x1 - 2, 0)), 60);
    bool sh = (xb1 != xb0);
    float wA[16], wB[16];
#pragma unroll
    for (int i = 0; i < 16; ++i) {     // compile-time indices only
        wA[i] = wlds[x0 * 17 + i];
        wB[i] = wlds[x1 * 17 + i];
    }

    const float* ob = outp + ((size_t)n * 256 + cg * 64) * 4096 + ybase * 64;
    float* rb = res + ((size_t)n * 256 + cg * 64) * 16384 + y * 128 + x0;

    // prologue: batch 0 into named regs (ch = cq + 4k, 16B coalesced per wave)
    f32x4 g0 = *(const f32x4*)(ob + (size_t)(cq + 0)  * 4096 + seg * 4);
    f32x4 g1 = *(const f32x4*)(ob + (size_t)(cq + 4)  * 4096 + seg * 4);
    f32x4 g2 = *(const f32x4*)(ob + (size_t)(cq + 8)  * 4096 + seg * 4);
    f32x4 g3 = *(const f32x4*)(ob + (size_t)(cq + 12) * 4096 + seg * 4);

#pragma unroll 1
    for (int batch = 0; batch < 4; ++batch) {
        __syncthreads();               // previous compute done before tile overwrite
        *(f32x4*)&tile[(cq + 0)  * 260 + seg * 4] = g0;
        *(f32x4*)&tile[(cq + 4)  * 260 + seg * 4] = g1;
        *(f32x4*)&tile[(cq + 8)  * 260 + seg * 4] = g2;
        *(f32x4*)&tile[(cq + 12) * 260 + seg * 4] = g3;
        __syncthreads();
        if (batch < 3) {               // issue next batch loads; consumed next iteration
            const float* s2 = ob + (size_t)(batch + 1) * 16 * 4096;
            g0 = *(const f32x4*)(s2 + (size_t)(cq + 0)  * 4096 + seg * 4);
            g1 = *(const f32x4*)(s2 + (size_t)(cq + 4)  * 4096 + seg * 4);
            g2 = *(const f32x4*)(s2 + (size_t)(cq + 8)  * 4096 + seg * 4);
            g3 = *(const f32x4*)(s2 + (size_t)(cq + 12) * 4096 + seg * 4);
        }
#pragma unroll
        for (int cc = 0; cc < 4; ++cc) {
            int c = cq * 4 + cc;       // local channel in tile
            const float* tp = &tile[c * 260 + xb0];
            float a0 = 0.f, a1 = 0.f;
#pragma unroll
            for (int r = 0; r < 4; ++r) {
                float c0 = tp[r * 64 + 0];
                float c1 = tp[r * 64 + 1];
                float c2 = tp[r * 64 + 2];
                float c3 = tp[r * 64 + 3];
                float c4 = tp[r * 64 + 4];     // padded tile row: always in bounds
                a0 = fmaf(wA[r*4+0], c0, a0);
                a0 = fmaf(wA[r*4+1], c1, a0);
                a0 = fmaf(wA[r*4+2], c2, a0);
                a0 = fmaf(wA[r*4+3], c3, a0);
                float s0 = sh ? c1 : c0;
                float s1 = sh ? c2 : c1;
                float s2v = sh ? c3 : c2;
                float s3 = sh ? c4 : c3;
                a1 = fmaf(wB[r*4+0], s0, a1);
                a1 = fmaf(wB[r*4+1], s1, a1);
                a1 = fmaf(wB[r*4+2], s2v, a1);
                a1 = fmaf(wB[r*4+3], s3, a1);
            }
            f32x2 st = { a0, a1 };
            *(f32x2*)(rb + (size_t)(batch * 16 + c) * 16384) = st;   // coalesced 8B store
        }
    }
}

extern "C" void kernel_launch(void* const* d_in, const int* in_sizes, int n_in,
                              void* d_out, int out_size, void* d_ws, size_t ws_size,
                              hipStream_t stream) {
    const float* c1   = (const float*)d_in[0];
    const float* c2   = (const float*)d_in[1];
    const float* outp = (const float*)d_in[2];
    const float* wr   = (const float*)d_in[3];
    const float* wr2  = (const float*)d_in[4];
    float* res = (float*)d_out;

    // ws: kfs 2.10MB | kft 8.39MB | wbuf 4.19MB
    float* kfs_ws = (float*)d_ws;
    float* kft_ws = (float*)((char*)d_ws + 2097152);
    float* w_ws   = (float*)((char*)d_ws + 2097152 + 8388608);

    hipLaunchKernelGGL(k_kfs,    dim3(256),  dim3(1024), 0, stream, c2, wr2, kfs_ws);
    hipLaunchKernelGGL(k_upnorm, dim3(1024), dim3(256),  0, stream, kfs_ws, kft_ws);
    hipLaunchKernelGGL(k_fq3,    dim3(512),  dim3(512),  0, stream, c1, wr, kft_ws, w_ws);
    hipLaunchKernelGGL(k_agg4,   dim3(2048), dim3(256),  0, stream, w_ws, outp, res);
}